// Round 3
// baseline (472.789 us; speedup 1.0000x reference)
//
#include <hip/hip_runtime.h>

// B=8, T=1024, D=1024, H=16, Dh=64. Input float dtype UNKNOWN (fp32 per the
// reference text vs bf16 per the test label) -> runtime probe + dual-dtype
// loads. Output stored in the same dtype the probe detects. lengths int32.
//
// Pipeline:
//   0. probe_k: detect fp32 vs bf16 from x's bit patterns -> flag in ws
//   1. transpose w_qkv -> wT_qkv [3072,1024] bf16 (dtype-aware load)
//   2. transpose w_o   -> wT_o   [1024,1024] bf16
//   3. GEMM1 qkv = x@w_qkv+b -> Q,K [bh,1024,64] bf16; V -> VT [bh,64,1024]
//   4. attention (no-max softmax, exact length mask) -> O [rows,1024] bf16
//   5. GEMM2 out = O@w_o + b_o -> d_out (fp32 or bf16 per flag)
// ws_size-adaptive: full pipeline (~76 MB) or per-batch loop (~17 MB).

typedef __attribute__((ext_vector_type(8))) short bf16x8;
typedef __attribute__((ext_vector_type(4))) float f32x4;

__device__ inline short f2b(float f) {
  unsigned u = __float_as_uint(f);
  unsigned r = (u + 0x7fff + ((u >> 16) & 1)) >> 16;
  return (short)r;
}
__device__ inline float b2f(short s) {
  return __uint_as_float(((unsigned)(unsigned short)s) << 16);
}

// load 8 contiguous values as bf16x8 from either an fp32 or bf16 buffer.
// p must point at the FIRST element's byte address.
__device__ inline bf16x8 ld8(const char* p, int isf32) {
  if (isf32) {
    const float* f = (const float*)p;
    bf16x8 r;
#pragma unroll
    for (int j = 0; j < 8; j++) r[j] = f2b(f[j]);
    return r;
  }
  return *(const bf16x8*)p;
}

__device__ inline float ldbias(const char* b, int n, int isf32) {
  return isf32 ? ((const float*)b)[n] : b2f(((const short*)b)[n]);
}

// ---------------- dtype probe ----------------------------------------------
// If x is fp32, shorts at even indices are low mantissa bits (uniform) ->
// ~44% have bf16-exponent >= 0x90 (|v| >= 2^17). If x is bf16 N(0,1) data,
// none do. Count over 1024 words; flag=1 means fp32.
__global__ void probe_k(const short* __restrict__ xs, int* __restrict__ flag) {
  if (threadIdx.x == 0) {
    int cnt = 0;
    for (int i = 0; i < 1024; i++) {
      int e = (xs[2 * i] >> 7) & 0xFF;
      cnt += (e >= 0x90) ? 1 : 0;
    }
    *flag = (cnt > 100) ? 1 : 0;
  }
}

// ---------------- transpose: out[c][r] = in[r][c], in dtype-aware -----------
__global__ __launch_bounds__(256) void transpose_k(const char* __restrict__ in,
                                                   short* __restrict__ out,
                                                   int R, int C,
                                                   const int* __restrict__ flag) {
  __shared__ __align__(16) short tile[64][80];
  int isf32 = *flag;
  size_t esz = isf32 ? 4 : 2;
  int t = threadIdx.x;
  int r0 = blockIdx.y * 64, c0 = blockIdx.x * 64;
#pragma unroll
  for (int i = 0; i < 2; i++) {
    int s = i * 256 + t;
    int rr = s >> 3;
    int cc = (s & 7) * 8;
    *(bf16x8*)&tile[rr][cc] =
        ld8(in + ((size_t)(r0 + rr) * C + c0 + cc) * esz, isf32);
  }
  __syncthreads();
#pragma unroll
  for (int i = 0; i < 2; i++) {
    int s = i * 256 + t;
    int cc2 = s >> 3;
    int rr2 = (s & 7) * 8;
    bf16x8 v;
#pragma unroll
    for (int j = 0; j < 8; j++) v[j] = tile[rr2 + j][cc2];
    *(bf16x8*)(out + (size_t)(c0 + cc2) * R + r0 + rr2) = v;
  }
}

// ---------------- GEMM core: C[128x128] = A[M,1024] @ Bt[N,1024]^T ----------
// A is dtype-aware (byte pointer + esz); Bt is bf16. 4 waves 2x2, each wave
// 64x64 = 4x4 mfma 16x16x32 tiles. Plain vector-load->LDS staging.
__device__ inline void gemm_core(const char* __restrict__ A, int isf32,
                                 const short* __restrict__ Bt, short* As,
                                 short* Bs, int m0, int n0, f32x4 acc[4][4]) {
  const int K = 1024;
  int t = threadIdx.x;
  int lane = t & 63, wave = t >> 6, quad = lane >> 4, col = lane & 15;
  int wm = (wave >> 1) * 64, wn = (wave & 1) * 64;
  int lrow = t >> 2, lk = (t & 3) * 8;
  size_t esz = isf32 ? 4 : 2;
  const char* Ab = A + (size_t)m0 * K * esz;
  const short* Bb = Bt + (size_t)n0 * K;
  for (int kt = 0; kt < K; kt += 32) {
    bf16x8 a0 = ld8(Ab + ((size_t)lrow * K + kt + lk) * esz, isf32);
    bf16x8 a1 = ld8(Ab + ((size_t)(lrow + 64) * K + kt + lk) * esz, isf32);
    bf16x8 b0 = *(const bf16x8*)(Bb + (size_t)lrow * K + kt + lk);
    bf16x8 b1 = *(const bf16x8*)(Bb + (size_t)(lrow + 64) * K + kt + lk);
    *(bf16x8*)(As + lrow * 32 + lk) = a0;
    *(bf16x8*)(As + (lrow + 64) * 32 + lk) = a1;
    *(bf16x8*)(Bs + lrow * 32 + lk) = b0;
    *(bf16x8*)(Bs + (lrow + 64) * 32 + lk) = b1;
    __syncthreads();
    bf16x8 af[4], bfr[4];
#pragma unroll
    for (int i = 0; i < 4; i++)
      af[i] = *(const bf16x8*)(As + (wm + i * 16 + col) * 32 + quad * 8);
#pragma unroll
    for (int i = 0; i < 4; i++)
      bfr[i] = *(const bf16x8*)(Bs + (wn + i * 16 + col) * 32 + quad * 8);
#pragma unroll
    for (int i = 0; i < 4; i++)
#pragma unroll
      for (int j = 0; j < 4; j++)
        acc[i][j] = __builtin_amdgcn_mfma_f32_16x16x32_bf16(af[i], bfr[j],
                                                            acc[i][j], 0, 0, 0);
    __syncthreads();
  }
}

// GEMM1. Grid (24, nb*8). Q,K,VT buffers hold nb batches (b_base offset).
__global__ __launch_bounds__(256, 2) void gemm_qkv_k(
    const char* __restrict__ x, const short* __restrict__ wT,
    const char* __restrict__ bias, short* __restrict__ Qb,
    short* __restrict__ Kb, short* __restrict__ VTb,
    const int* __restrict__ flag, int b_base) {
  __shared__ __align__(16) short As[128 * 32];
  __shared__ __align__(16) short Bs[128 * 32];
  int isf32 = *flag;
  f32x4 acc[4][4];
#pragma unroll
  for (int i = 0; i < 4; i++)
#pragma unroll
    for (int j = 0; j < 4; j++) acc[i][j] = f32x4{0.f, 0.f, 0.f, 0.f};
  int m0 = blockIdx.y * 128, n0 = blockIdx.x * 128;
  size_t esz = isf32 ? 4 : 2;
  const char* xb = x + (size_t)b_base * 1024 * 1024 * esz;
  gemm_core(xb, isf32, wT, As, Bs, m0, n0, acc);
  int t = threadIdx.x, wave = t >> 6, lane = t & 63, quad = lane >> 4,
      col = lane & 15;
  int wm = (wave >> 1) * 64, wn = (wave & 1) * 64;
#pragma unroll
  for (int j = 0; j < 4; j++) {
    int n = n0 + wn + j * 16 + col;
    float bv = ldbias(bias, n, isf32);
    int qi = n >> 10, d = n & 1023, h = d >> 6, dh = d & 63;
#pragma unroll
    for (int i = 0; i < 4; i++) {
#pragma unroll
      for (int r = 0; r < 4; r++) {
        int m = m0 + wm + i * 16 + quad * 4 + r;  // local row in this group
        int bl = m >> 10, tp = m & 1023;          // local batch, time
        size_t bh = (size_t)bl * 16 + h;
        float val = acc[i][j][r] + bv;
        if (qi == 0)
          Qb[(bh * 1024 + tp) * 64 + dh] = f2b(val);
        else if (qi == 1)
          Kb[(bh * 1024 + tp) * 64 + dh] = f2b(val);
        else
          VTb[(bh * 64 + dh) * 1024 + tp] = f2b(val);
      }
    }
  }
}

// attention. Grid (16, nb*16). Each wave owns 16 q-rows; no-max softmax.
__global__ __launch_bounds__(256, 2) void attn_k(
    const short* __restrict__ Qb, const short* __restrict__ Kb,
    const short* __restrict__ VTb, const int* __restrict__ lengths,
    short* __restrict__ Ob, int b_base) {
  __shared__ __align__(16) short Pl[4 * 16 * 40];
  int t = threadIdx.x, wave = t >> 6, lane = t & 63, quad = lane >> 4,
      col = lane & 15;
  int bh = blockIdx.y, bl = bh >> 4, h = bh & 15;
  int len = lengths[b_base + bl];
  int q0 = blockIdx.x * 64 + wave * 16;
  const short* Q = Qb + (size_t)bh * 1024 * 64;
  const short* K = Kb + (size_t)bh * 1024 * 64;
  const short* VT = VTb + (size_t)bh * 64 * 1024;
  short* myP = Pl + wave * 16 * 40;

  bf16x8 qf0 = *(const bf16x8*)(Q + (q0 + col) * 64 + quad * 8);
  bf16x8 qf1 = *(const bf16x8*)(Q + (q0 + col) * 64 + 32 + quad * 8);

  f32x4 oacc[4];
  float suml[4] = {0.f, 0.f, 0.f, 0.f};
#pragma unroll
  for (int i = 0; i < 4; i++) oacc[i] = f32x4{0.f, 0.f, 0.f, 0.f};

  int klim = ((len + 31) >> 5) << 5;  // block-uniform
  for (int k0 = 0; k0 < klim; k0 += 32) {
    f32x4 s0 = f32x4{0.f, 0.f, 0.f, 0.f};
    f32x4 s1 = f32x4{0.f, 0.f, 0.f, 0.f};
    bf16x8 kf;
    kf = *(const bf16x8*)(K + (k0 + col) * 64 + quad * 8);
    s0 = __builtin_amdgcn_mfma_f32_16x16x32_bf16(qf0, kf, s0, 0, 0, 0);
    kf = *(const bf16x8*)(K + (k0 + col) * 64 + 32 + quad * 8);
    s0 = __builtin_amdgcn_mfma_f32_16x16x32_bf16(qf1, kf, s0, 0, 0, 0);
    kf = *(const bf16x8*)(K + (k0 + 16 + col) * 64 + quad * 8);
    s1 = __builtin_amdgcn_mfma_f32_16x16x32_bf16(qf0, kf, s1, 0, 0, 0);
    kf = *(const bf16x8*)(K + (k0 + 16 + col) * 64 + 32 + quad * 8);
    s1 = __builtin_amdgcn_mfma_f32_16x16x32_bf16(qf1, kf, s1, 0, 0, 0);
#pragma unroll
    for (int r = 0; r < 4; r++) {
      int row = quad * 4 + r;
      float e0 = (k0 + col < len) ? __expf(s0[r] * 0.125f) : 0.f;
      float e1 = (k0 + 16 + col < len) ? __expf(s1[r] * 0.125f) : 0.f;
      suml[r] += e0 + e1;
      myP[row * 40 + col] = f2b(e0);
      myP[row * 40 + 16 + col] = f2b(e1);
    }
    __syncthreads();
    bf16x8 pf = *(const bf16x8*)(myP + col * 40 + quad * 8);
#pragma unroll
    for (int nt = 0; nt < 4; nt++) {
      bf16x8 vf = *(const bf16x8*)(VT + (nt * 16 + col) * 1024 + k0 + quad * 8);
      oacc[nt] =
          __builtin_amdgcn_mfma_f32_16x16x32_bf16(pf, vf, oacc[nt], 0, 0, 0);
    }
    __syncthreads();
  }
#pragma unroll
  for (int r = 0; r < 4; r++) {
    suml[r] += __shfl_xor(suml[r], 1);
    suml[r] += __shfl_xor(suml[r], 2);
    suml[r] += __shfl_xor(suml[r], 4);
    suml[r] += __shfl_xor(suml[r], 8);
  }
#pragma unroll
  for (int nt = 0; nt < 4; nt++) {
#pragma unroll
    for (int r = 0; r < 4; r++) {
      int q = q0 + quad * 4 + r;
      float v = (q < len) ? oacc[nt][r] / suml[r] : 0.f;
      Ob[((size_t)bl * 1024 + q) * 1024 + h * 64 + nt * 16 + col] = f2b(v);
    }
  }
}

// GEMM2. Grid (8, nb*8). Output dtype follows flag.
__global__ __launch_bounds__(256, 2) void gemm_out_k(
    const short* __restrict__ O, const short* __restrict__ wT,
    const char* __restrict__ bias, char* __restrict__ out,
    const int* __restrict__ flag, int m_base) {
  __shared__ __align__(16) short As[128 * 32];
  __shared__ __align__(16) short Bs[128 * 32];
  int isf32 = *flag;
  f32x4 acc[4][4];
#pragma unroll
  for (int i = 0; i < 4; i++)
#pragma unroll
    for (int j = 0; j < 4; j++) acc[i][j] = f32x4{0.f, 0.f, 0.f, 0.f};
  int m0 = blockIdx.y * 128, n0 = blockIdx.x * 128;
  gemm_core((const char*)O, 0, wT, As, Bs, m0, n0, acc);
  int t = threadIdx.x, wave = t >> 6, lane = t & 63, quad = lane >> 4,
      col = lane & 15;
  int wm = (wave >> 1) * 64, wn = (wave & 1) * 64;
#pragma unroll
  for (int j = 0; j < 4; j++) {
    int n = n0 + wn + j * 16 + col;
    float bv = ldbias(bias, n, isf32);
#pragma unroll
    for (int i = 0; i < 4; i++) {
#pragma unroll
      for (int r = 0; r < 4; r++) {
        int m = m0 + wm + i * 16 + quad * 4 + r;
        size_t idx = (size_t)(m_base + m) * 1024 + n;
        float val = acc[i][j][r] + bv;
        if (isf32)
          ((float*)out)[idx] = val;
        else
          ((short*)out)[idx] = f2b(val);
      }
    }
  }
}

extern "C" void kernel_launch(void* const* d_in, const int* in_sizes, int n_in,
                              void* d_out, int out_size, void* d_ws,
                              size_t ws_size, hipStream_t stream) {
  const char* x = (const char*)d_in[0];      // [8,1024,1024] fp32 or bf16
  const int* lengths = (const int*)d_in[1];  // [8] int32
  const char* w_qkv = (const char*)d_in[2];  // [1024,3072]
  const char* b_qkv = (const char*)d_in[3];  // [3072]
  const char* w_o = (const char*)d_in[4];    // [1024,1024]
  const char* b_o = (const char*)d_in[5];    // [1024]
  char* out = (char*)d_out;                  // [8,1024,1024]

  // ws layout
  char* ws = (char*)d_ws;
  int* flag = (int*)ws;                 ws += 256;
  short* wT_qkv = (short*)ws;           ws += (size_t)3072 * 1024 * 2;  // 6.3M
  short* wT_o = (short*)ws;             ws += (size_t)1024 * 1024 * 2;  // 2.1M
  char* dynbase = ws;
  size_t fixed = (size_t)(dynbase - (char*)d_ws);
  // per-batch-group buffers: nb batches => Q,K,VT,Ob each nb*16*1024*64 shorts
  size_t per_batch = (size_t)16 * 1024 * 64 * 2;  // 2.10 MB per tensor
  size_t need_full = fixed + 4 * 8 * per_batch;   // ~75.8 MB
  int nb = (ws_size >= need_full) ? 8 : 1;

  short* Qb = (short*)dynbase;
  short* Kb = Qb + (size_t)nb * 16 * 1024 * 64;
  short* VTb = Kb + (size_t)nb * 16 * 1024 * 64;
  short* Ob = VTb + (size_t)nb * 16 * 64 * 1024;

  dim3 blk(256);
  probe_k<<<1, 64, 0, stream>>>((const short*)x, flag);
  transpose_k<<<dim3(48, 16), blk, 0, stream>>>(w_qkv, wT_qkv, 1024, 3072, flag);
  transpose_k<<<dim3(16, 16), blk, 0, stream>>>(w_o, wT_o, 1024, 1024, flag);
  for (int b0 = 0; b0 < 8; b0 += nb) {
    gemm_qkv_k<<<dim3(24, nb * 8), blk, 0, stream>>>(x, wT_qkv, b_qkv, Qb, Kb,
                                                     VTb, flag, b0);
    attn_k<<<dim3(16, nb * 16), blk, 0, stream>>>(Qb, Kb, VTb, lengths, Ob, b0);
    gemm_out_k<<<dim3(8, nb * 8), blk, 0, stream>>>(Ob, wT_o, b_o, out, flag,
                                                    b0 * 1024);
  }
}

// Round 4
// 408.279 us; speedup vs baseline: 1.1580x; 1.1580x over previous
//
#include <hip/hip_runtime.h>

// B=8, T=1024, D=1024, H=16, Dh=64. x/w/b are fp32 (probe-verified R3; dual
// path kept for robustness), lengths int32, output dtype follows probe flag.
//
// Pipeline:
//   0. probe_k: fp32-vs-bf16 flag (1 wave)
//   1. cvt_x: x -> xbf bf16 [rows,1024]            (aliases Ob)
//   2. transpose w_qkv -> wT_qkv [3072,1024] bf16; w_o -> wT_o [1024,1024]
//   3. GEMM1 (m97 global_load_lds staging): qkv = xbf@w+b
//        -> Q (pre-scaled by 1/8), K [bh,1024,64]; V -> VT [bh,64,1024]
//   4. attn: barrier-free wave-private flash (no-max softmax, exact mask)
//        -> Ob [rows,1024] (overwrites xbf)
//   5. GEMM2: out = Ob@w_o + b_o -> d_out (fp32 or bf16 per flag)

typedef __attribute__((ext_vector_type(8))) short bf16x8;
typedef __attribute__((ext_vector_type(4))) float f32x4;

__device__ inline short f2b(float f) {
  unsigned u = __float_as_uint(f);
  unsigned r = (u + 0x7fff + ((u >> 16) & 1)) >> 16;
  return (short)r;
}
__device__ inline float b2f(short s) {
  return __uint_as_float(((unsigned)(unsigned short)s) << 16);
}

__device__ inline bf16x8 ld8(const char* p, int isf32) {
  if (isf32) {
    const float* f = (const float*)p;
    bf16x8 r;
#pragma unroll
    for (int j = 0; j < 8; j++) r[j] = f2b(f[j]);
    return r;
  }
  return *(const bf16x8*)p;
}

__device__ inline float ldbias(const char* b, int n, int isf32) {
  return isf32 ? ((const float*)b)[n] : b2f(((const short*)b)[n]);
}

__device__ inline void gl_lds16(const short* g, short* l) {
  __builtin_amdgcn_global_load_lds(
      (const __attribute__((address_space(1))) void*)g,
      (__attribute__((address_space(3))) void*)l, 16, 0, 0);
}

// ---------------- dtype probe (1 block x 64) --------------------------------
__global__ void probe_k(const short* __restrict__ xs, int* __restrict__ flag) {
  int lane = threadIdx.x & 63;
  int cnt = 0;
  for (int i = lane; i < 1024; i += 64) {
    int e = (xs[2 * i] >> 7) & 0xFF;
    cnt += (e >= 0x90) ? 1 : 0;
  }
#pragma unroll
  for (int o = 1; o < 64; o <<= 1) cnt += __shfl_xor(cnt, o);
  if (lane == 0) *flag = (cnt > 100) ? 1 : 0;
}

// ---------------- x -> bf16 (nb*512 blocks x 256) ---------------------------
__global__ __launch_bounds__(256) void cvt_x_k(const char* __restrict__ x,
                                               short* __restrict__ xb,
                                               const int* __restrict__ flag,
                                               int b_base) {
  int isf32 = *flag;
  size_t esz = isf32 ? 4 : 2;
  size_t i = ((size_t)blockIdx.x * 256 + threadIdx.x) * 8;
  size_t g = (size_t)b_base * 1024 * 1024 + i;
  *(bf16x8*)(xb + i) = ld8(x + g * esz, isf32);
}

// ---------------- transpose out[c][r] = in[r][c] ----------------------------
__global__ __launch_bounds__(256) void transpose_k(
    const char* __restrict__ in, short* __restrict__ out, int R, int C,
    const int* __restrict__ flag) {
  __shared__ __align__(16) short tile[64][80];
  int isf32 = *flag;
  size_t esz = isf32 ? 4 : 2;
  int t = threadIdx.x;
  int r0 = blockIdx.y * 64, c0 = blockIdx.x * 64;
#pragma unroll
  for (int i = 0; i < 2; i++) {
    int s = i * 256 + t;
    int rr = s >> 3, cc = (s & 7) * 8;
    *(bf16x8*)&tile[rr][cc] =
        ld8(in + ((size_t)(r0 + rr) * C + c0 + cc) * esz, isf32);
  }
  __syncthreads();
#pragma unroll
  for (int i = 0; i < 2; i++) {
    int s = i * 256 + t;
    int cc2 = s >> 3, rr2 = (s & 7) * 8;
    bf16x8 v;
#pragma unroll
    for (int j = 0; j < 8; j++) v[j] = tile[rr2 + j][cc2];
    *(bf16x8*)(out + (size_t)(c0 + cc2) * R + r0 + rr2) = v;
  }
}

// ---------------- GEMM core (m97 structure): C[128x128]=A@Bt^T, K=1024 ------
__device__ inline void gemm_core(const short* __restrict__ A,
                                 const short* __restrict__ Bt, short* As,
                                 short* Bs, int m0, int n0, f32x4 acc[4][4]) {
  const int K = 1024;
  int t = threadIdx.x;
  int lane = t & 63, wave = t >> 6, quad = lane >> 4, col = lane & 15;
  int wm = (wave >> 1) * 64, wn = (wave & 1) * 64;
  int lrow = t >> 2, lk = (t & 3) * 8;
  const short* Ab = A + (size_t)m0 * K;
  const short* Bb = Bt + (size_t)n0 * K;
  for (int kt = 0; kt < K; kt += 32) {
    gl_lds16(Ab + (size_t)lrow * K + kt + lk, As + t * 8);
    gl_lds16(Ab + (size_t)(lrow + 64) * K + kt + lk, As + 2048 + t * 8);
    gl_lds16(Bb + (size_t)lrow * K + kt + lk, Bs + t * 8);
    gl_lds16(Bb + (size_t)(lrow + 64) * K + kt + lk, Bs + 2048 + t * 8);
    __syncthreads();
    bf16x8 af[4], bfr[4];
#pragma unroll
    for (int i = 0; i < 4; i++)
      af[i] = *(const bf16x8*)(As + (wm + i * 16 + col) * 32 + quad * 8);
#pragma unroll
    for (int i = 0; i < 4; i++)
      bfr[i] = *(const bf16x8*)(Bs + (wn + i * 16 + col) * 32 + quad * 8);
#pragma unroll
    for (int i = 0; i < 4; i++)
#pragma unroll
      for (int j = 0; j < 4; j++)
        acc[i][j] = __builtin_amdgcn_mfma_f32_16x16x32_bf16(af[i], bfr[j],
                                                            acc[i][j], 0, 0, 0);
    __syncthreads();
  }
}

// GEMM1. Grid (24, nb*8). Q is pre-scaled by 0.125 (exact power of two).
__global__ __launch_bounds__(256, 2) void gemm_qkv_k(
    const short* __restrict__ xbf, const short* __restrict__ wT,
    const char* __restrict__ bias, short* __restrict__ Qb,
    short* __restrict__ Kb, short* __restrict__ VTb,
    const int* __restrict__ flag) {
  __shared__ __align__(16) short As[128 * 32];
  __shared__ __align__(16) short Bs[128 * 32];
  int isf32 = *flag;
  f32x4 acc[4][4];
#pragma unroll
  for (int i = 0; i < 4; i++)
#pragma unroll
    for (int j = 0; j < 4; j++) acc[i][j] = f32x4{0.f, 0.f, 0.f, 0.f};
  int m0 = blockIdx.y * 128, n0 = blockIdx.x * 128;
  gemm_core(xbf, wT, As, Bs, m0, n0, acc);
  int t = threadIdx.x, wave = t >> 6, lane = t & 63, quad = lane >> 4,
      col = lane & 15;
  int wm = (wave >> 1) * 64, wn = (wave & 1) * 64;
#pragma unroll
  for (int j = 0; j < 4; j++) {
    int n = n0 + wn + j * 16 + col;
    float bv = ldbias(bias, n, isf32);
    int qi = n >> 10, d = n & 1023, h = d >> 6, dh = d & 63;
#pragma unroll
    for (int i = 0; i < 4; i++) {
#pragma unroll
      for (int r = 0; r < 4; r++) {
        int m = m0 + wm + i * 16 + quad * 4 + r;
        int bl = m >> 10, tp = m & 1023;
        size_t bh = (size_t)bl * 16 + h;
        float val = acc[i][j][r] + bv;
        if (qi == 0)
          Qb[(bh * 1024 + tp) * 64 + dh] = f2b(val * 0.125f);
        else if (qi == 1)
          Kb[(bh * 1024 + tp) * 64 + dh] = f2b(val);
        else
          VTb[(bh * 64 + dh) * 1024 + tp] = f2b(val);
      }
    }
  }
}

// attention. Grid (16, nb*16). Barrier-free: P region is wave-private; wave
// lockstep + compiler lgkmcnt ordering make the LDS round-trip safe.
__global__ __launch_bounds__(256, 2) void attn_k(
    const short* __restrict__ Qb, const short* __restrict__ Kb,
    const short* __restrict__ VTb, const int* __restrict__ lengths,
    short* __restrict__ Ob, int b_base) {
  __shared__ __align__(16) short Pl[4 * 16 * 80];
  int t = threadIdx.x, wave = t >> 6, lane = t & 63, quad = lane >> 4,
      col = lane & 15;
  int bh = blockIdx.y, bl = bh >> 4, h = bh & 15;
  int len = lengths[b_base + bl];
  int q0 = blockIdx.x * 64 + wave * 16;
  const short* Q = Qb + (size_t)bh * 1024 * 64;
  const short* K = Kb + (size_t)bh * 1024 * 64;
  const short* VT = VTb + (size_t)bh * 64 * 1024;
  short* myP = Pl + wave * 16 * 80;  // rows 16, stride 80 (16B-aligned rows)

  bf16x8 qf0 = *(const bf16x8*)(Q + (q0 + col) * 64 + quad * 8);
  bf16x8 qf1 = *(const bf16x8*)(Q + (q0 + col) * 64 + 32 + quad * 8);

  f32x4 oacc[4];
  float suml[4] = {0.f, 0.f, 0.f, 0.f};
#pragma unroll
  for (int i = 0; i < 4; i++) oacc[i] = f32x4{0.f, 0.f, 0.f, 0.f};

  int klim = ((len + 63) >> 6) << 6;  // block-uniform, <= 1024
  for (int k0 = 0; k0 < klim; k0 += 64) {
    f32x4 s[4];
#pragma unroll
    for (int ks = 0; ks < 4; ks++) s[ks] = f32x4{0.f, 0.f, 0.f, 0.f};
#pragma unroll
    for (int ks = 0; ks < 4; ks++) {
      bf16x8 klo = *(const bf16x8*)(K + (k0 + ks * 16 + col) * 64 + quad * 8);
      bf16x8 khi =
          *(const bf16x8*)(K + (k0 + ks * 16 + col) * 64 + 32 + quad * 8);
      s[ks] = __builtin_amdgcn_mfma_f32_16x16x32_bf16(qf0, klo, s[ks], 0, 0, 0);
      s[ks] = __builtin_amdgcn_mfma_f32_16x16x32_bf16(qf1, khi, s[ks], 0, 0, 0);
    }
#pragma unroll
    for (int ks = 0; ks < 4; ks++) {
#pragma unroll
      for (int r = 0; r < 4; r++) {
        float e = (k0 + ks * 16 + col < len) ? __expf(s[ks][r]) : 0.f;
        suml[r] += e;
        myP[(quad * 4 + r) * 80 + ks * 16 + col] = f2b(e);
      }
    }
    // P exits QK in C-layout; re-read in A-layout (within-wave transpose).
    bf16x8 pf0 = *(const bf16x8*)(myP + col * 80 + quad * 8);
    bf16x8 pf1 = *(const bf16x8*)(myP + col * 80 + 32 + quad * 8);
#pragma unroll
    for (int nt = 0; nt < 4; nt++) {
      bf16x8 v0 = *(const bf16x8*)(VT + (nt * 16 + col) * 1024 + k0 + quad * 8);
      oacc[nt] = __builtin_amdgcn_mfma_f32_16x16x32_bf16(pf0, v0, oacc[nt], 0, 0, 0);
      bf16x8 v1 =
          *(const bf16x8*)(VT + (nt * 16 + col) * 1024 + k0 + 32 + quad * 8);
      oacc[nt] = __builtin_amdgcn_mfma_f32_16x16x32_bf16(pf1, v1, oacc[nt], 0, 0, 0);
    }
  }
#pragma unroll
  for (int r = 0; r < 4; r++) {
    suml[r] += __shfl_xor(suml[r], 1);
    suml[r] += __shfl_xor(suml[r], 2);
    suml[r] += __shfl_xor(suml[r], 4);
    suml[r] += __shfl_xor(suml[r], 8);
  }
#pragma unroll
  for (int nt = 0; nt < 4; nt++) {
#pragma unroll
    for (int r = 0; r < 4; r++) {
      int q = q0 + quad * 4 + r;
      float v = (q < len) ? oacc[nt][r] / suml[r] : 0.f;
      Ob[((size_t)bl * 1024 + q) * 1024 + h * 64 + nt * 16 + col] = f2b(v);
    }
  }
}

// GEMM2. Grid (8, nb*8). Output dtype follows flag.
__global__ __launch_bounds__(256, 2) void gemm_out_k(
    const short* __restrict__ O, const short* __restrict__ wT,
    const char* __restrict__ bias, char* __restrict__ out,
    const int* __restrict__ flag, int m_base) {
  __shared__ __align__(16) short As[128 * 32];
  __shared__ __align__(16) short Bs[128 * 32];
  int isf32 = *flag;
  f32x4 acc[4][4];
#pragma unroll
  for (int i = 0; i < 4; i++)
#pragma unroll
    for (int j = 0; j < 4; j++) acc[i][j] = f32x4{0.f, 0.f, 0.f, 0.f};
  int m0 = blockIdx.y * 128, n0 = blockIdx.x * 128;
  gemm_core(O, wT, As, Bs, m0, n0, acc);
  int t = threadIdx.x, wave = t >> 6, lane = t & 63, quad = lane >> 4,
      col = lane & 15;
  int wm = (wave >> 1) * 64, wn = (wave & 1) * 64;
#pragma unroll
  for (int j = 0; j < 4; j++) {
    int n = n0 + wn + j * 16 + col;
    float bv = ldbias(bias, n, isf32);
#pragma unroll
    for (int i = 0; i < 4; i++) {
#pragma unroll
      for (int r = 0; r < 4; r++) {
        int m = m0 + wm + i * 16 + quad * 4 + r;
        size_t idx = (size_t)(m_base + m) * 1024 + n;
        float val = acc[i][j][r] + bv;
        if (isf32)
          ((float*)out)[idx] = val;
        else
          ((short*)out)[idx] = f2b(val);
      }
    }
  }
}

extern "C" void kernel_launch(void* const* d_in, const int* in_sizes, int n_in,
                              void* d_out, int out_size, void* d_ws,
                              size_t ws_size, hipStream_t stream) {
  const char* x = (const char*)d_in[0];
  const int* lengths = (const int*)d_in[1];
  const char* w_qkv = (const char*)d_in[2];
  const char* b_qkv = (const char*)d_in[3];
  const char* w_o = (const char*)d_in[4];
  const char* b_o = (const char*)d_in[5];
  char* out = (char*)d_out;

  char* ws = (char*)d_ws;
  int* flag = (int*)ws;        ws += 256;
  short* wT_qkv = (short*)ws;  ws += (size_t)3072 * 1024 * 2;  // 6.3 MB
  short* wT_o = (short*)ws;    ws += (size_t)1024 * 1024 * 2;  // 2.1 MB
  char* dynbase = ws;
  size_t fixed = (size_t)(dynbase - (char*)d_ws);
  size_t per_batch = (size_t)16 * 1024 * 64 * 2;       // 2.10 MB / tensor
  size_t need_full = fixed + 4 * 8 * per_batch;        // ~75.8 MB (fit in R3)
  int nb = (ws_size >= need_full) ? 8 : 1;

  // xbf aliases Ob: x is consumed by GEMM1 before attn writes Ob.
  short* xbf_Ob = (short*)dynbase;
  short* Qb = xbf_Ob + (size_t)nb * 16 * 1024 * 64;
  short* Kb = Qb + (size_t)nb * 16 * 1024 * 64;
  short* VTb = Kb + (size_t)nb * 16 * 1024 * 64;

  dim3 blk(256);
  probe_k<<<1, 64, 0, stream>>>((const short*)x, flag);
  transpose_k<<<dim3(48, 16), blk, 0, stream>>>(w_qkv, wT_qkv, 1024, 3072, flag);
  transpose_k<<<dim3(16, 16), blk, 0, stream>>>(w_o, wT_o, 1024, 1024, flag);
  for (int b0 = 0; b0 < 8; b0 += nb) {
    cvt_x_k<<<dim3(nb * 512), blk, 0, stream>>>(x, xbf_Ob, flag, b0);
    gemm_qkv_k<<<dim3(24, nb * 8), blk, 0, stream>>>(xbf_Ob, wT_qkv, b_qkv, Qb,
                                                     Kb, VTb, flag);
    attn_k<<<dim3(16, nb * 16), blk, 0, stream>>>(Qb, Kb, VTb, lengths, xbf_Ob,
                                                  b0);
    gemm_out_k<<<dim3(8, nb * 8), blk, 0, stream>>>(xbf_Ob, wT_o, b_o, out,
                                                    flag, b0 * 1024);
  }
}

// Round 5
// 279.380 us; speedup vs baseline: 1.6923x; 1.4614x over previous
//
#include <hip/hip_runtime.h>

// B=8, T=1024, D=1024, H=16, Dh=64. x/w/b fp32 (probe-verified; dual path
// kept), lengths int32, output dtype follows probe flag.
//
// Pipeline:
//   0. probe_k: fp32-vs-bf16 flag (1 wave)
//   1. cvt_x: x -> xbf bf16 (aliases Ob)
//   2. transpose w_qkv -> wT_qkv; w_o -> wT_o (bf16)
//   3. GEMM1 (m97 global_load_lds): Q(x0.125), K [bh,1024,64]; V->VT[bh,64,1024]
//   4. attn: per-block LDS-staged K/VT tiles (m97-style async staging),
//      no-max softmax, exact length mask -> Ob
//   5. GEMM2: out = Ob@w_o + b_o
//
// R5: attn rewritten — R4 was latency-bound (MfmaUtil 4.9%, VALUBusy 13.5%):
// 16 per-wave global dwordx4 gathers/iter with no VGPR headroom to pipeline.
// Now K/VT tiles are staged to LDS once per block via global_load_lds.

typedef __attribute__((ext_vector_type(8))) short bf16x8;
typedef __attribute__((ext_vector_type(4))) float f32x4;

__device__ inline short f2b(float f) {
  unsigned u = __float_as_uint(f);
  unsigned r = (u + 0x7fff + ((u >> 16) & 1)) >> 16;
  return (short)r;
}
__device__ inline float b2f(short s) {
  return __uint_as_float(((unsigned)(unsigned short)s) << 16);
}

__device__ inline bf16x8 ld8(const char* p, int isf32) {
  if (isf32) {
    const float* f = (const float*)p;
    bf16x8 r;
#pragma unroll
    for (int j = 0; j < 8; j++) r[j] = f2b(f[j]);
    return r;
  }
  return *(const bf16x8*)p;
}

__device__ inline float ldbias(const char* b, int n, int isf32) {
  return isf32 ? ((const float*)b)[n] : b2f(((const short*)b)[n]);
}

__device__ inline void gl_lds16(const short* g, short* l) {
  __builtin_amdgcn_global_load_lds(
      (const __attribute__((address_space(1))) void*)g,
      (__attribute__((address_space(3))) void*)l, 16, 0, 0);
}

// ---------------- dtype probe (1 block x 64) --------------------------------
__global__ void probe_k(const short* __restrict__ xs, int* __restrict__ flag) {
  int lane = threadIdx.x & 63;
  int cnt = 0;
  for (int i = lane; i < 1024; i += 64) {
    int e = (xs[2 * i] >> 7) & 0xFF;
    cnt += (e >= 0x90) ? 1 : 0;
  }
#pragma unroll
  for (int o = 1; o < 64; o <<= 1) cnt += __shfl_xor(cnt, o);
  if (lane == 0) *flag = (cnt > 100) ? 1 : 0;
}

// ---------------- x -> bf16 -------------------------------------------------
__global__ __launch_bounds__(256) void cvt_x_k(const char* __restrict__ x,
                                               short* __restrict__ xb,
                                               const int* __restrict__ flag,
                                               int b_base) {
  int isf32 = *flag;
  size_t esz = isf32 ? 4 : 2;
  size_t i = ((size_t)blockIdx.x * 256 + threadIdx.x) * 8;
  size_t g = (size_t)b_base * 1024 * 1024 + i;
  *(bf16x8*)(xb + i) = ld8(x + g * esz, isf32);
}

// ---------------- transpose out[c][r] = in[r][c] ----------------------------
__global__ __launch_bounds__(256) void transpose_k(
    const char* __restrict__ in, short* __restrict__ out, int R, int C,
    const int* __restrict__ flag) {
  __shared__ __align__(16) short tile[64][80];
  int isf32 = *flag;
  size_t esz = isf32 ? 4 : 2;
  int t = threadIdx.x;
  int r0 = blockIdx.y * 64, c0 = blockIdx.x * 64;
#pragma unroll
  for (int i = 0; i < 2; i++) {
    int s = i * 256 + t;
    int rr = s >> 3, cc = (s & 7) * 8;
    *(bf16x8*)&tile[rr][cc] =
        ld8(in + ((size_t)(r0 + rr) * C + c0 + cc) * esz, isf32);
  }
  __syncthreads();
#pragma unroll
  for (int i = 0; i < 2; i++) {
    int s = i * 256 + t;
    int cc2 = s >> 3, rr2 = (s & 7) * 8;
    bf16x8 v;
#pragma unroll
    for (int j = 0; j < 8; j++) v[j] = tile[rr2 + j][cc2];
    *(bf16x8*)(out + (size_t)(c0 + cc2) * R + r0 + rr2) = v;
  }
}

// ---------------- GEMM core (m97): C[128x128]=A@Bt^T, K=1024 ----------------
__device__ inline void gemm_core(const short* __restrict__ A,
                                 const short* __restrict__ Bt, short* As,
                                 short* Bs, int m0, int n0, f32x4 acc[4][4]) {
  const int K = 1024;
  int t = threadIdx.x;
  int lane = t & 63, wave = t >> 6, quad = lane >> 4, col = lane & 15;
  int wm = (wave >> 1) * 64, wn = (wave & 1) * 64;
  int lrow = t >> 2, lk = (t & 3) * 8;
  const short* Ab = A + (size_t)m0 * K;
  const short* Bb = Bt + (size_t)n0 * K;
  for (int kt = 0; kt < K; kt += 32) {
    gl_lds16(Ab + (size_t)lrow * K + kt + lk, As + t * 8);
    gl_lds16(Ab + (size_t)(lrow + 64) * K + kt + lk, As + 2048 + t * 8);
    gl_lds16(Bb + (size_t)lrow * K + kt + lk, Bs + t * 8);
    gl_lds16(Bb + (size_t)(lrow + 64) * K + kt + lk, Bs + 2048 + t * 8);
    __syncthreads();
    bf16x8 af[4], bfr[4];
#pragma unroll
    for (int i = 0; i < 4; i++)
      af[i] = *(const bf16x8*)(As + (wm + i * 16 + col) * 32 + quad * 8);
#pragma unroll
    for (int i = 0; i < 4; i++)
      bfr[i] = *(const bf16x8*)(Bs + (wn + i * 16 + col) * 32 + quad * 8);
#pragma unroll
    for (int i = 0; i < 4; i++)
#pragma unroll
      for (int j = 0; j < 4; j++)
        acc[i][j] = __builtin_amdgcn_mfma_f32_16x16x32_bf16(af[i], bfr[j],
                                                            acc[i][j], 0, 0, 0);
    __syncthreads();
  }
}

// GEMM1. Grid (24, nb*8). Q pre-scaled by 0.125 (exact).
__global__ __launch_bounds__(256, 2) void gemm_qkv_k(
    const short* __restrict__ xbf, const short* __restrict__ wT,
    const char* __restrict__ bias, short* __restrict__ Qb,
    short* __restrict__ Kb, short* __restrict__ VTb,
    const int* __restrict__ flag) {
  __shared__ __align__(16) short As[128 * 32];
  __shared__ __align__(16) short Bs[128 * 32];
  int isf32 = *flag;
  f32x4 acc[4][4];
#pragma unroll
  for (int i = 0; i < 4; i++)
#pragma unroll
    for (int j = 0; j < 4; j++) acc[i][j] = f32x4{0.f, 0.f, 0.f, 0.f};
  int m0 = blockIdx.y * 128, n0 = blockIdx.x * 128;
  gemm_core(xbf, wT, As, Bs, m0, n0, acc);
  int t = threadIdx.x, wave = t >> 6, lane = t & 63, quad = lane >> 4,
      col = lane & 15;
  int wm = (wave >> 1) * 64, wn = (wave & 1) * 64;
#pragma unroll
  for (int j = 0; j < 4; j++) {
    int n = n0 + wn + j * 16 + col;
    float bv = ldbias(bias, n, isf32);
    int qi = n >> 10, d = n & 1023, h = d >> 6, dh = d & 63;
#pragma unroll
    for (int i = 0; i < 4; i++) {
#pragma unroll
      for (int r = 0; r < 4; r++) {
        int m = m0 + wm + i * 16 + quad * 4 + r;
        int bl = m >> 10, tp = m & 1023;
        size_t bh = (size_t)bl * 16 + h;
        float val = acc[i][j][r] + bv;
        if (qi == 0)
          Qb[(bh * 1024 + tp) * 64 + dh] = f2b(val * 0.125f);
        else if (qi == 1)
          Kb[(bh * 1024 + tp) * 64 + dh] = f2b(val);
        else
          VTb[(bh * 64 + dh) * 1024 + tp] = f2b(val);
      }
    }
  }
}

// attention. Grid (16, nb*16), 4 waves. K/VT tiles staged to LDS per block in
// m97 [rows][32] half-tile layout; P round-trip wave-private (stride 72,
// 2-way max on reads).
__global__ __launch_bounds__(256, 2) void attn_k(
    const short* __restrict__ Qb, const short* __restrict__ Kb,
    const short* __restrict__ VTb, const int* __restrict__ lengths,
    short* __restrict__ Ob, int b_base) {
  __shared__ __align__(16) short Ks[2][64 * 32];  // [half][key][d-within-half]
  __shared__ __align__(16) short Vs[2][64 * 32];  // [half][dh][k-within-half]
  __shared__ __align__(16) short Pl[4 * 16 * 72];
  int t = threadIdx.x, wave = t >> 6, lane = t & 63, quad = lane >> 4,
      col = lane & 15;
  int bh = blockIdx.y, bl = bh >> 4, h = bh & 15;
  int len = lengths[b_base + bl];
  int q0 = blockIdx.x * 64 + wave * 16;
  const short* Q = Qb + (size_t)bh * 1024 * 64;
  const short* K = Kb + (size_t)bh * 1024 * 64;
  const short* VT = VTb + (size_t)bh * 64 * 1024;
  short* myP = Pl + wave * 16 * 72;

  bf16x8 qf0 = *(const bf16x8*)(Q + (q0 + col) * 64 + quad * 8);
  bf16x8 qf1 = *(const bf16x8*)(Q + (q0 + col) * 64 + 32 + quad * 8);

  f32x4 oacc[4];
  float suml[4] = {0.f, 0.f, 0.f, 0.f};
#pragma unroll
  for (int i = 0; i < 4; i++) oacc[i] = f32x4{0.f, 0.f, 0.f, 0.f};

  int srow = t >> 2, skk = (t & 3) * 8;  // staging: row t>>2, 8-elem k-span
  int klim = ((len + 63) >> 6) << 6;     // block-uniform, <= 1024
  for (int k0 = 0; k0 < klim; k0 += 64) {
    // stage K[k0..k0+63][0..63] and VT[0..63][k0..k0+63] as 32-wide halves
    gl_lds16(K + (size_t)(k0 + srow) * 64 + skk, Ks[0] + t * 8);
    gl_lds16(K + (size_t)(k0 + srow) * 64 + 32 + skk, Ks[1] + t * 8);
    gl_lds16(VT + (size_t)srow * 1024 + k0 + skk, Vs[0] + t * 8);
    gl_lds16(VT + (size_t)srow * 1024 + k0 + 32 + skk, Vs[1] + t * 8);
    __syncthreads();

    f32x4 s[4];
#pragma unroll
    for (int ks = 0; ks < 4; ks++) s[ks] = f32x4{0.f, 0.f, 0.f, 0.f};
#pragma unroll
    for (int ks = 0; ks < 4; ks++) {
      bf16x8 klo = *(const bf16x8*)(Ks[0] + (ks * 16 + col) * 32 + quad * 8);
      bf16x8 khi = *(const bf16x8*)(Ks[1] + (ks * 16 + col) * 32 + quad * 8);
      s[ks] = __builtin_amdgcn_mfma_f32_16x16x32_bf16(qf0, klo, s[ks], 0, 0, 0);
      s[ks] = __builtin_amdgcn_mfma_f32_16x16x32_bf16(qf1, khi, s[ks], 0, 0, 0);
    }
#pragma unroll
    for (int ks = 0; ks < 4; ks++) {
#pragma unroll
      for (int r = 0; r < 4; r++) {
        float e = (k0 + ks * 16 + col < len) ? __expf(s[ks][r]) : 0.f;
        suml[r] += e;
        myP[(quad * 4 + r) * 72 + ks * 16 + col] = f2b(e);
      }
    }
    // C-layout -> A-layout via wave-private LDS round trip
    bf16x8 pf0 = *(const bf16x8*)(myP + col * 72 + quad * 8);
    bf16x8 pf1 = *(const bf16x8*)(myP + col * 72 + 32 + quad * 8);
#pragma unroll
    for (int nt = 0; nt < 4; nt++) {
      bf16x8 v0 = *(const bf16x8*)(Vs[0] + (nt * 16 + col) * 32 + quad * 8);
      bf16x8 v1 = *(const bf16x8*)(Vs[1] + (nt * 16 + col) * 32 + quad * 8);
      oacc[nt] =
          __builtin_amdgcn_mfma_f32_16x16x32_bf16(pf0, v0, oacc[nt], 0, 0, 0);
      oacc[nt] =
          __builtin_amdgcn_mfma_f32_16x16x32_bf16(pf1, v1, oacc[nt], 0, 0, 0);
    }
    __syncthreads();
  }
#pragma unroll
  for (int r = 0; r < 4; r++) {
    suml[r] += __shfl_xor(suml[r], 1);
    suml[r] += __shfl_xor(suml[r], 2);
    suml[r] += __shfl_xor(suml[r], 4);
    suml[r] += __shfl_xor(suml[r], 8);
  }
#pragma unroll
  for (int nt = 0; nt < 4; nt++) {
#pragma unroll
    for (int r = 0; r < 4; r++) {
      int q = q0 + quad * 4 + r;
      float v = (q < len) ? oacc[nt][r] / suml[r] : 0.f;
      Ob[((size_t)bl * 1024 + q) * 1024 + h * 64 + nt * 16 + col] = f2b(v);
    }
  }
}

// GEMM2. Grid (8, nb*8). Output dtype follows flag.
__global__ __launch_bounds__(256, 2) void gemm_out_k(
    const short* __restrict__ O, const short* __restrict__ wT,
    const char* __restrict__ bias, char* __restrict__ out,
    const int* __restrict__ flag, int m_base) {
  __shared__ __align__(16) short As[128 * 32];
  __shared__ __align__(16) short Bs[128 * 32];
  int isf32 = *flag;
  f32x4 acc[4][4];
#pragma unroll
  for (int i = 0; i < 4; i++)
#pragma unroll
    for (int j = 0; j < 4; j++) acc[i][j] = f32x4{0.f, 0.f, 0.f, 0.f};
  int m0 = blockIdx.y * 128, n0 = blockIdx.x * 128;
  gemm_core(O, wT, As, Bs, m0, n0, acc);
  int t = threadIdx.x, wave = t >> 6, lane = t & 63, quad = lane >> 4,
      col = lane & 15;
  int wm = (wave >> 1) * 64, wn = (wave & 1) * 64;
#pragma unroll
  for (int j = 0; j < 4; j++) {
    int n = n0 + wn + j * 16 + col;
    float bv = ldbias(bias, n, isf32);
#pragma unroll
    for (int i = 0; i < 4; i++) {
#pragma unroll
      for (int r = 0; r < 4; r++) {
        int m = m0 + wm + i * 16 + quad * 4 + r;
        size_t idx = (size_t)(m_base + m) * 1024 + n;
        float val = acc[i][j][r] + bv;
        if (isf32)
          ((float*)out)[idx] = val;
        else
          ((short*)out)[idx] = f2b(val);
      }
    }
  }
}

extern "C" void kernel_launch(void* const* d_in, const int* in_sizes, int n_in,
                              void* d_out, int out_size, void* d_ws,
                              size_t ws_size, hipStream_t stream) {
  const char* x = (const char*)d_in[0];
  const int* lengths = (const int*)d_in[1];
  const char* w_qkv = (const char*)d_in[2];
  const char* b_qkv = (const char*)d_in[3];
  const char* w_o = (const char*)d_in[4];
  const char* b_o = (const char*)d_in[5];
  char* out = (char*)d_out;

  char* ws = (char*)d_ws;
  int* flag = (int*)ws;        ws += 256;
  short* wT_qkv = (short*)ws;  ws += (size_t)3072 * 1024 * 2;  // 6.3 MB
  short* wT_o = (short*)ws;    ws += (size_t)1024 * 1024 * 2;  // 2.1 MB
  char* dynbase = ws;
  size_t fixed = (size_t)(dynbase - (char*)d_ws);
  size_t per_batch = (size_t)16 * 1024 * 64 * 2;  // 2.10 MB / tensor
  size_t need_full = fixed + 4 * 8 * per_batch;   // ~75.8 MB (fits, R3/R4)
  int nb = (ws_size >= need_full) ? 8 : 1;

  // xbf aliases Ob: x consumed by GEMM1 before attn writes Ob.
  short* xbf_Ob = (short*)dynbase;
  short* Qb = xbf_Ob + (size_t)nb * 16 * 1024 * 64;
  short* Kb = Qb + (size_t)nb * 16 * 1024 * 64;
  short* VTb = Kb + (size_t)nb * 16 * 1024 * 64;

  dim3 blk(256);
  probe_k<<<1, 64, 0, stream>>>((const short*)x, flag);
  transpose_k<<<dim3(48, 16), blk, 0, stream>>>(w_qkv, wT_qkv, 1024, 3072, flag);
  transpose_k<<<dim3(16, 16), blk, 0, stream>>>(w_o, wT_o, 1024, 1024, flag);
  for (int b0 = 0; b0 < 8; b0 += nb) {
    cvt_x_k<<<dim3(nb * 512), blk, 0, stream>>>(x, xbf_Ob, flag, b0);
    gemm_qkv_k<<<dim3(24, nb * 8), blk, 0, stream>>>(xbf_Ob, wT_qkv, b_qkv, Qb,
                                                     Kb, VTb, flag);
    attn_k<<<dim3(16, nb * 16), blk, 0, stream>>>(Qb, Kb, VTb, lengths, xbf_Ob,
                                                  b0);
    gemm_out_k<<<dim3(8, nb * 8), blk, 0, stream>>>(xbf_Ob, wT_o, b_o, out,
                                                    flag, b0 * 1024);
  }
}

// Round 6
// 264.925 us; speedup vs baseline: 1.7846x; 1.0546x over previous
//
#include <hip/hip_runtime.h>

// B=8, T=1024, D=1024, H=16, Dh=64. x/w/b fp32 (probe-verified; dual path
// kept), lengths int32, output dtype follows probe flag.
//
// R6: R5 counters showed gemm_qkv 80% stalled (MfmaUtil 19.8%, occupancy 27%
// ~= 2.2 blocks/CU; barrier drain uncovered). Changes:
//   - GEMM core BK=64: 32 mfma per barrier pair (2x), 32 KB LDS
//   - __launch_bounds__(256,4) so 4 blocks/CU are schedulable
//   - attn: 32 q-rows/wave (2x mfma per staged tile), 4 blocks/CU

typedef __attribute__((ext_vector_type(8))) short bf16x8;
typedef __attribute__((ext_vector_type(4))) float f32x4;

__device__ inline short f2b(float f) {
  unsigned u = __float_as_uint(f);
  unsigned r = (u + 0x7fff + ((u >> 16) & 1)) >> 16;
  return (short)r;
}
__device__ inline float b2f(short s) {
  return __uint_as_float(((unsigned)(unsigned short)s) << 16);
}

__device__ inline bf16x8 ld8(const char* p, int isf32) {
  if (isf32) {
    const float* f = (const float*)p;
    bf16x8 r;
#pragma unroll
    for (int j = 0; j < 8; j++) r[j] = f2b(f[j]);
    return r;
  }
  return *(const bf16x8*)p;
}

__device__ inline float ldbias(const char* b, int n, int isf32) {
  return isf32 ? ((const float*)b)[n] : b2f(((const short*)b)[n]);
}

__device__ inline void gl_lds16(const short* g, short* l) {
  __builtin_amdgcn_global_load_lds(
      (const __attribute__((address_space(1))) void*)g,
      (__attribute__((address_space(3))) void*)l, 16, 0, 0);
}

// ---------------- dtype probe (1 block x 64) --------------------------------
__global__ void probe_k(const short* __restrict__ xs, int* __restrict__ flag) {
  int lane = threadIdx.x & 63;
  int cnt = 0;
  for (int i = lane; i < 1024; i += 64) {
    int e = (xs[2 * i] >> 7) & 0xFF;
    cnt += (e >= 0x90) ? 1 : 0;
  }
#pragma unroll
  for (int o = 1; o < 64; o <<= 1) cnt += __shfl_xor(cnt, o);
  if (lane == 0) *flag = (cnt > 100) ? 1 : 0;
}

// ---------------- x -> bf16 -------------------------------------------------
__global__ __launch_bounds__(256) void cvt_x_k(const char* __restrict__ x,
                                               short* __restrict__ xb,
                                               const int* __restrict__ flag,
                                               int b_base) {
  int isf32 = *flag;
  size_t esz = isf32 ? 4 : 2;
  size_t i = ((size_t)blockIdx.x * 256 + threadIdx.x) * 8;
  size_t g = (size_t)b_base * 1024 * 1024 + i;
  *(bf16x8*)(xb + i) = ld8(x + g * esz, isf32);
}

// ---------------- transpose out[c][r] = in[r][c] ----------------------------
__global__ __launch_bounds__(256) void transpose_k(
    const char* __restrict__ in, short* __restrict__ out, int R, int C,
    const int* __restrict__ flag) {
  __shared__ __align__(16) short tile[64][80];
  int isf32 = *flag;
  size_t esz = isf32 ? 4 : 2;
  int t = threadIdx.x;
  int r0 = blockIdx.y * 64, c0 = blockIdx.x * 64;
#pragma unroll
  for (int i = 0; i < 2; i++) {
    int s = i * 256 + t;
    int rr = s >> 3, cc = (s & 7) * 8;
    *(bf16x8*)&tile[rr][cc] =
        ld8(in + ((size_t)(r0 + rr) * C + c0 + cc) * esz, isf32);
  }
  __syncthreads();
#pragma unroll
  for (int i = 0; i < 2; i++) {
    int s = i * 256 + t;
    int cc2 = s >> 3, rr2 = (s & 7) * 8;
    bf16x8 v;
#pragma unroll
    for (int j = 0; j < 8; j++) v[j] = tile[rr2 + j][cc2];
    *(bf16x8*)(out + (size_t)(c0 + cc2) * R + r0 + rr2) = v;
  }
}

// ---------------- GEMM core BK=64: C[128x128]=A@Bt^T, K=1024 ----------------
// Two 32-wide k-chunks staged per barrier pair: 32 mfma / barrier.
__device__ inline void gemm_core(const short* __restrict__ A,
                                 const short* __restrict__ Bt, short* As,
                                 short* Bs, int m0, int n0, f32x4 acc[4][4]) {
  const int K = 1024;
  int t = threadIdx.x;
  int lane = t & 63, wave = t >> 6, quad = lane >> 4, col = lane & 15;
  int wm = (wave >> 1) * 64, wn = (wave & 1) * 64;
  int lrow = t >> 2, lk = (t & 3) * 8;
  const short* Ab = A + (size_t)m0 * K;
  const short* Bb = Bt + (size_t)n0 * K;
  for (int kt = 0; kt < K; kt += 64) {
#pragma unroll
    for (int c = 0; c < 2; c++) {
      int kc = kt + c * 32;
      gl_lds16(Ab + (size_t)lrow * K + kc + lk, As + c * 4096 + t * 8);
      gl_lds16(Ab + (size_t)(lrow + 64) * K + kc + lk,
               As + c * 4096 + 2048 + t * 8);
      gl_lds16(Bb + (size_t)lrow * K + kc + lk, Bs + c * 4096 + t * 8);
      gl_lds16(Bb + (size_t)(lrow + 64) * K + kc + lk,
               Bs + c * 4096 + 2048 + t * 8);
    }
    __syncthreads();
#pragma unroll
    for (int c = 0; c < 2; c++) {
      bf16x8 af[4], bfr[4];
#pragma unroll
      for (int i = 0; i < 4; i++)
        af[i] = *(const bf16x8*)(As + c * 4096 + (wm + i * 16 + col) * 32 +
                                 quad * 8);
#pragma unroll
      for (int i = 0; i < 4; i++)
        bfr[i] = *(const bf16x8*)(Bs + c * 4096 + (wn + i * 16 + col) * 32 +
                                  quad * 8);
#pragma unroll
      for (int i = 0; i < 4; i++)
#pragma unroll
        for (int j = 0; j < 4; j++)
          acc[i][j] = __builtin_amdgcn_mfma_f32_16x16x32_bf16(
              af[i], bfr[j], acc[i][j], 0, 0, 0);
    }
    __syncthreads();
  }
}

// GEMM1. Grid (24, nb*8). Q pre-scaled by 0.125 (exact).
__global__ __launch_bounds__(256, 4) void gemm_qkv_k(
    const short* __restrict__ xbf, const short* __restrict__ wT,
    const char* __restrict__ bias, short* __restrict__ Qb,
    short* __restrict__ Kb, short* __restrict__ VTb,
    const int* __restrict__ flag) {
  __shared__ __align__(16) short As[128 * 64];
  __shared__ __align__(16) short Bs[128 * 64];
  int isf32 = *flag;
  f32x4 acc[4][4];
#pragma unroll
  for (int i = 0; i < 4; i++)
#pragma unroll
    for (int j = 0; j < 4; j++) acc[i][j] = f32x4{0.f, 0.f, 0.f, 0.f};
  int m0 = blockIdx.y * 128, n0 = blockIdx.x * 128;
  gemm_core(xbf, wT, As, Bs, m0, n0, acc);
  int t = threadIdx.x, wave = t >> 6, lane = t & 63, quad = lane >> 4,
      col = lane & 15;
  int wm = (wave >> 1) * 64, wn = (wave & 1) * 64;
#pragma unroll
  for (int j = 0; j < 4; j++) {
    int n = n0 + wn + j * 16 + col;
    float bv = ldbias(bias, n, isf32);
    int qi = n >> 10, d = n & 1023, h = d >> 6, dh = d & 63;
#pragma unroll
    for (int i = 0; i < 4; i++) {
#pragma unroll
      for (int r = 0; r < 4; r++) {
        int m = m0 + wm + i * 16 + quad * 4 + r;
        int bl = m >> 10, tp = m & 1023;
        size_t bh = (size_t)bl * 16 + h;
        float val = acc[i][j][r] + bv;
        if (qi == 0)
          Qb[(bh * 1024 + tp) * 64 + dh] = f2b(val * 0.125f);
        else if (qi == 1)
          Kb[(bh * 1024 + tp) * 64 + dh] = f2b(val);
        else
          VTb[(bh * 64 + dh) * 1024 + tp] = f2b(val);
      }
    }
  }
}

// attention. Grid (8, nb*16), 4 waves; each wave owns 32 q-rows (2 q-tiles).
// K/VT tiles (64 keys) staged once per block iter; P wave-private (no
// barrier needed for its round-trip).
__global__ __launch_bounds__(256, 4) void attn_k(
    const short* __restrict__ Qb, const short* __restrict__ Kb,
    const short* __restrict__ VTb, const int* __restrict__ lengths,
    short* __restrict__ Ob, int b_base) {
  __shared__ __align__(16) short Ks[2][64 * 32];  // [half][key][d-in-half]
  __shared__ __align__(16) short Vs[2][64 * 32];  // [half][dh][k-in-half]
  __shared__ __align__(16) short Pl[4 * 32 * 72];
  int t = threadIdx.x, wave = t >> 6, lane = t & 63, quad = lane >> 4,
      col = lane & 15;
  int bh = blockIdx.y, bl = bh >> 4, h = bh & 15;
  int len = lengths[b_base + bl];
  int qb0 = blockIdx.x * 128 + wave * 16;  // qt adds +64
  const short* Q = Qb + (size_t)bh * 1024 * 64;
  const short* K = Kb + (size_t)bh * 1024 * 64;
  const short* VT = VTb + (size_t)bh * 64 * 1024;
  short* myP = Pl + wave * 32 * 72;  // 2 q-tiles x 16 rows, stride 72

  bf16x8 qf[2][2];
#pragma unroll
  for (int qt = 0; qt < 2; qt++) {
    qf[qt][0] = *(const bf16x8*)(Q + (qb0 + qt * 64 + col) * 64 + quad * 8);
    qf[qt][1] =
        *(const bf16x8*)(Q + (qb0 + qt * 64 + col) * 64 + 32 + quad * 8);
  }

  f32x4 oacc[2][4];
  float suml[2][4];
#pragma unroll
  for (int qt = 0; qt < 2; qt++)
#pragma unroll
    for (int i = 0; i < 4; i++) {
      oacc[qt][i] = f32x4{0.f, 0.f, 0.f, 0.f};
      suml[qt][i] = 0.f;
    }

  int srow = t >> 2, skk = (t & 3) * 8;
  int klim = ((len + 63) >> 6) << 6;  // block-uniform, <= 1024
  for (int k0 = 0; k0 < klim; k0 += 64) {
    gl_lds16(K + (size_t)(k0 + srow) * 64 + skk, Ks[0] + t * 8);
    gl_lds16(K + (size_t)(k0 + srow) * 64 + 32 + skk, Ks[1] + t * 8);
    gl_lds16(VT + (size_t)srow * 1024 + k0 + skk, Vs[0] + t * 8);
    gl_lds16(VT + (size_t)srow * 1024 + k0 + 32 + skk, Vs[1] + t * 8);
    __syncthreads();

#pragma unroll
    for (int qt = 0; qt < 2; qt++) {
      f32x4 s[4];
#pragma unroll
      for (int ks = 0; ks < 4; ks++) s[ks] = f32x4{0.f, 0.f, 0.f, 0.f};
#pragma unroll
      for (int ks = 0; ks < 4; ks++) {
        bf16x8 klo = *(const bf16x8*)(Ks[0] + (ks * 16 + col) * 32 + quad * 8);
        bf16x8 khi = *(const bf16x8*)(Ks[1] + (ks * 16 + col) * 32 + quad * 8);
        s[ks] = __builtin_amdgcn_mfma_f32_16x16x32_bf16(qf[qt][0], klo, s[ks],
                                                        0, 0, 0);
        s[ks] = __builtin_amdgcn_mfma_f32_16x16x32_bf16(qf[qt][1], khi, s[ks],
                                                        0, 0, 0);
      }
#pragma unroll
      for (int ks = 0; ks < 4; ks++) {
#pragma unroll
        for (int r = 0; r < 4; r++) {
          float e = (k0 + ks * 16 + col < len) ? __expf(s[ks][r]) : 0.f;
          suml[qt][r] += e;
          myP[(qt * 16 + quad * 4 + r) * 72 + ks * 16 + col] = f2b(e);
        }
      }
    }
    // C-layout -> A-layout via wave-private LDS round trip, then PV.
#pragma unroll
    for (int qt = 0; qt < 2; qt++) {
      bf16x8 pf0 = *(const bf16x8*)(myP + (qt * 16 + col) * 72 + quad * 8);
      bf16x8 pf1 = *(const bf16x8*)(myP + (qt * 16 + col) * 72 + 32 + quad * 8);
#pragma unroll
      for (int nt = 0; nt < 4; nt++) {
        bf16x8 v0 = *(const bf16x8*)(Vs[0] + (nt * 16 + col) * 32 + quad * 8);
        bf16x8 v1 = *(const bf16x8*)(Vs[1] + (nt * 16 + col) * 32 + quad * 8);
        oacc[qt][nt] = __builtin_amdgcn_mfma_f32_16x16x32_bf16(
            pf0, v0, oacc[qt][nt], 0, 0, 0);
        oacc[qt][nt] = __builtin_amdgcn_mfma_f32_16x16x32_bf16(
            pf1, v1, oacc[qt][nt], 0, 0, 0);
      }
    }
    __syncthreads();
  }
#pragma unroll
  for (int qt = 0; qt < 2; qt++)
#pragma unroll
    for (int r = 0; r < 4; r++) {
      suml[qt][r] += __shfl_xor(suml[qt][r], 1);
      suml[qt][r] += __shfl_xor(suml[qt][r], 2);
      suml[qt][r] += __shfl_xor(suml[qt][r], 4);
      suml[qt][r] += __shfl_xor(suml[qt][r], 8);
    }
#pragma unroll
  for (int qt = 0; qt < 2; qt++)
#pragma unroll
    for (int nt = 0; nt < 4; nt++)
#pragma unroll
      for (int r = 0; r < 4; r++) {
        int q = qb0 + qt * 64 + quad * 4 + r;
        float v = (q < len) ? oacc[qt][nt][r] / suml[qt][r] : 0.f;
        Ob[((size_t)bl * 1024 + q) * 1024 + h * 64 + nt * 16 + col] = f2b(v);
      }
}

// GEMM2. Grid (8, nb*8). Output dtype follows flag.
__global__ __launch_bounds__(256, 4) void gemm_out_k(
    const short* __restrict__ O, const short* __restrict__ wT,
    const char* __restrict__ bias, char* __restrict__ out,
    const int* __restrict__ flag, int m_base) {
  __shared__ __align__(16) short As[128 * 64];
  __shared__ __align__(16) short Bs[128 * 64];
  int isf32 = *flag;
  f32x4 acc[4][4];
#pragma unroll
  for (int i = 0; i < 4; i++)
#pragma unroll
    for (int j = 0; j < 4; j++) acc[i][j] = f32x4{0.f, 0.f, 0.f, 0.f};
  int m0 = blockIdx.y * 128, n0 = blockIdx.x * 128;
  gemm_core(O, wT, As, Bs, m0, n0, acc);
  int t = threadIdx.x, wave = t >> 6, lane = t & 63, quad = lane >> 4,
      col = lane & 15;
  int wm = (wave >> 1) * 64, wn = (wave & 1) * 64;
#pragma unroll
  for (int j = 0; j < 4; j++) {
    int n = n0 + wn + j * 16 + col;
    float bv = ldbias(bias, n, isf32);
#pragma unroll
    for (int i = 0; i < 4; i++) {
#pragma unroll
      for (int r = 0; r < 4; r++) {
        int m = m0 + wm + i * 16 + quad * 4 + r;
        size_t idx = (size_t)(m_base + m) * 1024 + n;
        float val = acc[i][j][r] + bv;
        if (isf32)
          ((float*)out)[idx] = val;
        else
          ((short*)out)[idx] = f2b(val);
      }
    }
  }
}

extern "C" void kernel_launch(void* const* d_in, const int* in_sizes, int n_in,
                              void* d_out, int out_size, void* d_ws,
                              size_t ws_size, hipStream_t stream) {
  const char* x = (const char*)d_in[0];
  const int* lengths = (const int*)d_in[1];
  const char* w_qkv = (const char*)d_in[2];
  const char* b_qkv = (const char*)d_in[3];
  const char* w_o = (const char*)d_in[4];
  const char* b_o = (const char*)d_in[5];
  char* out = (char*)d_out;

  char* ws = (char*)d_ws;
  int* flag = (int*)ws;        ws += 256;
  short* wT_qkv = (short*)ws;  ws += (size_t)3072 * 1024 * 2;  // 6.3 MB
  short* wT_o = (short*)ws;    ws += (size_t)1024 * 1024 * 2;  // 2.1 MB
  char* dynbase = ws;
  size_t fixed = (size_t)(dynbase - (char*)d_ws);
  size_t per_batch = (size_t)16 * 1024 * 64 * 2;  // 2.10 MB / tensor
  size_t need_full = fixed + 4 * 8 * per_batch;   // ~75.8 MB (fits, R3-R5)
  int nb = (ws_size >= need_full) ? 8 : 1;

  // xbf aliases Ob: x consumed by GEMM1 before attn writes Ob.
  short* xbf_Ob = (short*)dynbase;
  short* Qb = xbf_Ob + (size_t)nb * 16 * 1024 * 64;
  short* Kb = Qb + (size_t)nb * 16 * 1024 * 64;
  short* VTb = Kb + (size_t)nb * 16 * 1024 * 64;

  dim3 blk(256);
  probe_k<<<1, 64, 0, stream>>>((const short*)x, flag);
  transpose_k<<<dim3(48, 16), blk, 0, stream>>>(w_qkv, wT_qkv, 1024, 3072, flag);
  transpose_k<<<dim3(16, 16), blk, 0, stream>>>(w_o, wT_o, 1024, 1024, flag);
  for (int b0 = 0; b0 < 8; b0 += nb) {
    cvt_x_k<<<dim3(nb * 512), blk, 0, stream>>>(x, xbf_Ob, flag, b0);
    gemm_qkv_k<<<dim3(24, nb * 8), blk, 0, stream>>>(xbf_Ob, wT_qkv, b_qkv, Qb,
                                                     Kb, VTb, flag);
    attn_k<<<dim3(8, nb * 16), blk, 0, stream>>>(Qb, Kb, VTb, lengths, xbf_Ob,
                                                 b0);
    gemm_out_k<<<dim3(8, nb * 8), blk, 0, stream>>>(xbf_Ob, wT_o, b_o, out,
                                                    flag, b0 * 1024);
  }
}